// Round 3
// baseline (111.036 us; speedup 1.0000x reference)
//
#include <hip/hip_runtime.h>
#include <hip/hip_fp16.h>

// FlowAlignedSmoothingEffect — round 7: 2 pixels/thread for 4-way march ILP.
//
// R6 post-mortem: kernel ~38us, issue+latency bound. The march is a serial
// dependent chain (pos -> ds_read ~120cy -> interp -> pos), 3 deep, with only
// 2 independent chains (the 2 directions) per thread. This round:
//  * 32x16 tile, 256 threads, 2 pixels/thread (tx and tx+16): 4 independent
//    chains interleaved per iteration -> 2x latency hiding per wave.
//  * staging amortization: 41x25 window = 1025 recs / 512 px = 2.00 rec/px
//    (was 2.44); blocks 8192 -> 4096; prologue/barrier amortize 2x.
//  * per-pixel march arithmetic BIT-IDENTICAL to R6 (pure replication).
//  * LDS records stay 8B split (tanw float2 exact f32 / colw packed f16);
//    row stride 41 recs = 82 words == 18 mod 32 keeps bank rotation.
//  * XCD-chunked bijective swizzle updated for 4096 wgs (4096 % 8 == 0).

#define HH 1024
#define WW 1024
#define CC 3
#define BB 2
#define NPIX (HH * WW)

#define TSX 32
#define TSY 16
#define HALO_LO 4
#define NWX 41             // 4 + 32 + 5
#define NWY 25             // 4 + 16 + 5
#define NREC (NWX * NWY)   // 1025

__device__ __forceinline__ __half2 h2(unsigned u) {
    __half2 r; *(unsigned*)&r = u; return r;
}

__global__ __launch_bounds__(256) void flow_smooth_lds(
    const float* __restrict__ x, const float* __restrict__ tng,
    const float* __restrict__ sigma, float* __restrict__ out)
{
    __shared__ float2 tanw[NREC];   // 8200 B, f32 tangent (exact)
    __shared__ uint2  colw[NREC];   // 8200 B, colors packed f16

    // ---- XCD-chunked bijective block swizzle (8 XCDs, 4096 wgs) ----
    const int id  = (int)blockIdx.x + ((int)blockIdx.y << 5) + ((int)blockIdx.z << 11);
    const int swz = ((id & 7) << 9) + (id >> 3);
    const int bx = swz & 31;
    const int by = (swz >> 5) & 63;
    const int b  = swz >> 11;

    const int tile_x0 = bx * TSX;
    const int tile_y0 = by * TSY;
    const int win_x0 = tile_x0 - HALO_LO;
    const int win_y0 = tile_y0 - HALO_LO;
    const bool border = (bx == 0) | (bx == 31) | (by == 0) | (by == 63);

    const float* __restrict__ xb  = x   + (size_t)b * CC * NPIX;
    const float* __restrict__ tbx = tng + (size_t)b * 2 * NPIX;
    const float* __restrict__ tby = tbx + NPIX;

    // ---- stage 41x25 window into LDS ----
    if (!border) {
        const int gbase = win_y0 * WW + win_x0;
        for (unsigned j = threadIdx.x; j < NREC; j += 256) {
            const int jy = (int)(j / NWX);
            const int jx = (int)j - jy * NWX;
            const int g = gbase + (jy << 10) + jx;
            tanw[j] = make_float2(tbx[g], tby[g]);
            const __half2 c01 = __floats2half2_rn(xb[g], xb[NPIX + g]);
            const __half2 c2p = __floats2half2_rn(xb[2 * NPIX + g], 0.f);
            uint2 r;
            r.x = *(const unsigned*)&c01;
            r.y = *(const unsigned*)&c2p;
            colw[j] = r;
        }
    } else {
        for (unsigned j = threadIdx.x; j < NREC; j += 256) {
            const int jy = (int)(j / NWX);
            const int jx = (int)j - jy * NWX;
            const int gy = min(max(win_y0 + jy, 0), HH - 1);
            const int gx = min(max(win_x0 + jx, 0), WW - 1);
            const int g = gy * WW + gx;
            tanw[j] = make_float2(tbx[g], tby[g]);
            const __half2 c01 = __floats2half2_rn(xb[g], xb[NPIX + g]);
            const __half2 c2p = __floats2half2_rn(xb[2 * NPIX + g], 0.f);
            uint2 r;
            r.x = *(const unsigned*)&c01;
            r.y = *(const unsigned*)&c2p;
            colw[j] = r;
        }
    }
    __syncthreads();

    // ---- per-pixel setup (2 pixels: tx and tx+16, same row) ----
    const int tx = threadIdx.x & 15;
    const int ty = threadIdx.x >> 4;
    const int iy = tile_y0 + ty;

    const float sig = sigma[b];
    const float half_width = 2.0f * sig;
    const float inv2s2 = 1.0f / (2.0f * sig * sig);
    const float step = (float)(1.0 / 0.3333);

    // per-batch-uniform Gaussian weights + live trip count (sigma < 6 => <= 3)
    const float r0 = step;
    const float r1 = r0 + step;
    const float r2 = r1 + step;
    const int nlive = (int)(r0 < half_width) + (int)(r1 < half_width) + (int)(r2 < half_width);
    const float kk0 = __expf(-r0 * r0 * inv2s2);
    const float kk1 = __expf(-r1 * r1 * inv2s2);
    const float kk2 = __expf(-r2 * r2 * inv2s2);

    const float invW = 1.0f / WW;
    const float invH = 1.0f / HH;

    int   ix[2], pix[2];
    float xc0[2], xc1[2], xc2[2];
    float acc0[2] = {0.f, 0.f}, acc1[2] = {0.f, 0.f};
    float acc2[2] = {0.f, 0.f}, accs[2] = {0.f, 0.f};
    float vx[2][2], vy[2][2], px[2][2], py[2][2];

    #pragma unroll
    for (int pp = 0; pp < 2; ++pp) {
        ix[pp] = tile_x0 + tx + pp * 16;
        pix[pp] = iy * WW + ix[pp];
        xc0[pp] = xb[pix[pp]];
        xc1[pp] = xb[NPIX + pix[pp]];
        xc2[pp] = xb[2 * NPIX + pix[pp]];
        const int cidx = (ty + HALO_LO) * NWX + (tx + pp * 16 + HALO_LO);
        const float2 tc = tanw[cidx];
        vx[pp][0] = tc.x;  vy[pp][0] = tc.y;
        vx[pp][1] = -tc.x; vy[pp][1] = -tc.y;
        const float p0x = ((float)ix[pp] + 0.5f) * invW;
        const float p0y = ((float)iy + 0.5f) * invH;
        px[pp][0] = p0x + vx[pp][0] * invW;  py[pp][0] = p0y + vy[pp][0] * invH;
        px[pp][1] = p0x + vx[pp][1] * invW;  py[pp][1] = p0y + vy[pp][1] * invH;
    }

    if (!border) {
        // ===== interior fast path =====
        const int winoff = win_y0 * NWX + win_x0;
        #pragma unroll
        for (int it = 0; it < 3; ++it) {
            if (it >= nlive) break;
            const float k = (it == 0) ? kk0 : (it == 1) ? kk1 : kk2;
            const bool need_t = (it + 1 < nlive);   // last live iter: march is dead
            #pragma unroll
            for (int pp = 0; pp < 2; ++pp) {
                #pragma unroll
                for (int c = 0; c < 2; ++c) {
                    const float fx = fmaf(px[pp][c], (float)WW, -0.5f);
                    const float fy = fmaf(py[pp][c], (float)HH, -0.5f);
                    const float x0f = floorf(fx);
                    const float y0f = floorf(fy);
                    const float wx = fx - x0f;
                    const float wy = fy - y0f;
                    const int idx = (int)y0f * NWX + (int)x0f - winoff;

                    const float wxm = 1.f - wx, wym = 1.f - wy;
                    const float w00 = wxm * wym, w01 = wx * wym;
                    const float w10 = wxm * wy,  w11 = wx * wy;

                    // packed-f16 color bilinear (accumulate in f32)
                    const uint2 q00 = colw[idx];
                    const uint2 q01 = colw[idx + 1];
                    const uint2 q10 = colw[idx + NWX];
                    const uint2 q11 = colw[idx + NWX + 1];
                    const __half2 h00 = __float2half2_rn(w00);
                    const __half2 h01 = __float2half2_rn(w01);
                    const __half2 h10 = __float2half2_rn(w10);
                    const __half2 h11 = __float2half2_rn(w11);
                    __half2 a01 = __hmul2(h00, h2(q00.x));
                    a01 = __hfma2(h01, h2(q01.x), a01);
                    a01 = __hfma2(h10, h2(q10.x), a01);
                    a01 = __hfma2(h11, h2(q11.x), a01);
                    __half2 a2 = __hmul2(h00, h2(q00.y));
                    a2 = __hfma2(h01, h2(q01.y), a2);
                    a2 = __hfma2(h10, h2(q10.y), a2);
                    a2 = __hfma2(h11, h2(q11.y), a2);
                    acc0[pp] = fmaf(k, __low2float(a01), acc0[pp]);
                    acc1[pp] = fmaf(k, __high2float(a01), acc1[pp]);
                    acc2[pp] = fmaf(k, __low2float(a2), acc2[pp]);

                    if (need_t) {
                        // exact-f32 tangent interp + coherence flip (R6-identical)
                        const float2 t00 = tanw[idx];
                        const float2 t01 = tanw[idx + 1];
                        const float2 t10 = tanw[idx + NWX];
                        const float2 t11 = tanw[idx + NWX + 1];
                        float tfx = t00.x * w00 + t01.x * w01 + t10.x * w10 + t11.x * w11;
                        float tfy = t00.y * w00 + t01.y * w01 + t10.y * w10 + t11.y * w11;
                        const float vt = vx[pp][c] * tfx + vy[pp][c] * tfy;
                        const unsigned sgn = __float_as_uint(vt) & 0x80000000u;
                        tfx = __uint_as_float(__float_as_uint(tfx) ^ sgn);
                        tfy = __uint_as_float(__float_as_uint(tfy) ^ sgn);
                        vx[pp][c] = tfx; vy[pp][c] = tfy;
                        px[pp][c] += tfx * invW;
                        py[pp][c] += tfy * invH;
                    }
                }
            }
        }
        // accs is block-uniform in the interior (inb always true)
        float ks = 0.f;
        if (nlive > 0) ks += kk0;
        if (nlive > 1) ks += kk1;
        if (nlive > 2) ks += kk2;
        accs[0] = 2.0f * ks;
        accs[1] = accs[0];
    } else {
        // ===== border path: exact reference clamp semantics =====
        #pragma unroll
        for (int it = 0; it < 3; ++it) {
            if (it >= nlive) break;
            const float k = (it == 0) ? kk0 : (it == 1) ? kk1 : kk2;
            #pragma unroll
            for (int pp = 0; pp < 2; ++pp) {
                #pragma unroll
                for (int c = 0; c < 2; ++c) {
                    const float fx = fmaf(px[pp][c], (float)WW, -0.5f);
                    const float fy = fmaf(py[pp][c], (float)HH, -0.5f);
                    const float x0f = floorf(fx);
                    const float y0f = floorf(fy);
                    const float wx = fx - x0f;      // weights from UNclamped floor
                    const float wy = fy - y0f;
                    int x0i = (int)x0f;
                    int y0i = (int)y0f;
                    x0i = min(max(x0i, 0), WW - 1); // clamp BEFORE +1 (ref order)
                    y0i = min(max(y0i, 0), HH - 1);
                    const int x1i = min(x0i + 1, WW - 1);
                    const int y1i = min(y0i + 1, HH - 1);

                    const int jx0 = x0i - win_x0;
                    const int jx1 = x1i - win_x0;
                    const int jy0 = y0i - win_y0;
                    const int jy1 = y1i - win_y0;
                    const int i00 = jy0 * NWX + jx0;
                    const int i01 = jy0 * NWX + jx1;
                    const int i10 = jy1 * NWX + jx0;
                    const int i11 = jy1 * NWX + jx1;

                    const float wxm = 1.f - wx, wym = 1.f - wy;
                    const float w00 = wxm * wym, w01 = wx * wym;
                    const float w10 = wxm * wy,  w11 = wx * wy;

                    const bool inb = (px[pp][c] >= 0.f) & (px[pp][c] < 1.f) &
                                     (py[pp][c] >= 0.f) & (py[pp][c] < 1.f);
                    const float kg = inb ? k : 0.f;

                    const uint2 q00 = colw[i00];
                    const uint2 q01 = colw[i01];
                    const uint2 q10 = colw[i10];
                    const uint2 q11 = colw[i11];
                    const __half2 h00 = __float2half2_rn(w00);
                    const __half2 h01 = __float2half2_rn(w01);
                    const __half2 h10 = __float2half2_rn(w10);
                    const __half2 h11 = __float2half2_rn(w11);
                    __half2 a01 = __hmul2(h00, h2(q00.x));
                    a01 = __hfma2(h01, h2(q01.x), a01);
                    a01 = __hfma2(h10, h2(q10.x), a01);
                    a01 = __hfma2(h11, h2(q11.x), a01);
                    __half2 a2 = __hmul2(h00, h2(q00.y));
                    a2 = __hfma2(h01, h2(q01.y), a2);
                    a2 = __hfma2(h10, h2(q10.y), a2);
                    a2 = __hfma2(h11, h2(q11.y), a2);
                    acc0[pp] = fmaf(kg, __low2float(a01), acc0[pp]);
                    acc1[pp] = fmaf(kg, __high2float(a01), acc1[pp]);
                    acc2[pp] = fmaf(kg, __low2float(a2), acc2[pp]);
                    accs[pp] += kg;

                    const float2 t00 = tanw[i00];
                    const float2 t01 = tanw[i01];
                    const float2 t10 = tanw[i10];
                    const float2 t11 = tanw[i11];
                    float tfx = t00.x * w00 + t01.x * w01 + t10.x * w10 + t11.x * w11;
                    float tfy = t00.y * w00 + t01.y * w01 + t10.y * w10 + t11.y * w11;
                    const float vt = vx[pp][c] * tfx + vy[pp][c] * tfy;
                    const unsigned sgn = __float_as_uint(vt) & 0x80000000u;
                    tfx = __uint_as_float(__float_as_uint(tfx) ^ sgn);
                    tfy = __uint_as_float(__float_as_uint(tfy) ^ sgn);
                    vx[pp][c] = tfx; vy[pp][c] = tfy;
                    px[pp][c] += tfx * invW;
                    py[pp][c] += tfy * invH;
                }
            }
        }
    }

    float* ob = out + (size_t)b * CC * NPIX;
    #pragma unroll
    for (int pp = 0; pp < 2; ++pp) {
        const float inv_den = 1.0f / (1.0f + accs[pp]);
        ob[pix[pp]]            = (xc0[pp] + acc0[pp]) * inv_den;
        ob[NPIX + pix[pp]]     = (xc1[pp] + acc1[pp]) * inv_den;
        ob[2 * NPIX + pix[pp]] = (xc2[pp] + acc2[pp]) * inv_den;
    }
}

extern "C" void kernel_launch(void* const* d_in, const int* in_sizes, int n_in,
                              void* d_out, int out_size, void* d_ws, size_t ws_size,
                              hipStream_t stream) {
    const float* x  = (const float*)d_in[0];
    const float* t  = (const float*)d_in[1];
    const float* sg = (const float*)d_in[2];
    float* out = (float*)d_out;

    dim3 grid(WW / TSX, HH / TSY, BB);
    flow_smooth_lds<<<grid, dim3(256), 0, stream>>>(x, t, sg, out);
}